// Round 1
// baseline (319.723 us; speedup 1.0000x reference)
//
#include <hip/hip_runtime.h>
#include <hip/hip_bf16.h>

// DenoisingPotential: x_{t+1} = x_t + alpha * grad_phi(x_t), 10 iters.
// grad = -(sum_k w_k * (P_k x - P_k mu_k)),  w = softmax(c - 0.5*quad)
// Restructured: s_k = e_k + (Pmu_k . x) - 0.5*(x . y_k), y_k = P_k x
// x += (alpha/l) * (sum_k wt_k Pmu_k - sum_k wt_k y_k),  wt = exp(s), l = sum wt
// (c=0 and quad>=0 => s<=0: no softmax max-shift needed)

typedef __attribute__((ext_vector_type(4))) float f32x4;
typedef __attribute__((ext_vector_type(8))) short bf16x8;  // 8 bf16 = 4 VGPRs

#define D 64
#define KC 32
#define NITER 10
#define XS_PAD 72  // bf16 elems per point-row in xs (pad to break b128 conflicts)

typedef __attribute__((address_space(3))) void as3_void;
typedef __attribute__((address_space(1))) const void as1_cvoid;

static __device__ __forceinline__ void gl_lds16(const void* g, void* l) {
  // per-lane gptr; LDS dest = wave-uniform base + lane*16 (HW semantics)
  __builtin_amdgcn_global_load_lds((as1_cvoid*)g, (as3_void*)l, 16, 0, 0);
}

// ---------------- precompute 1: per-k P = A^T A, Pmu, e, swizzled P ----------
__global__ void precompute1(const float* __restrict__ A, const float* __restrict__ mu,
                            const float* __restrict__ c,
                            float* __restrict__ Pmu_g, float* __restrict__ e_g,
                            __hip_bfloat16* __restrict__ Psw) {
  __shared__ float Pk[64 * 64];
  __shared__ float Pmu_s[64];
  const int k = blockIdx.x, tid = threadIdx.x;
  const float* Ak = A + k * 4096;
  for (int idx = tid; idx < 4096; idx += 256) {
    int i = idx >> 6, l = idx & 63;
    float s = 0.f;
    for (int j = 0; j < 64; ++j) s += Ak[j * 64 + i] * Ak[j * 64 + l];
    Pk[idx] = s;  // P[i][l], exactly symmetric
  }
  __syncthreads();
  if (tid < 64) {
    float s = 0.f;
    for (int l = 0; l < 64; ++l) s += Pk[tid * 64 + l] * mu[k * 64 + l];
    Pmu_s[tid] = s;
    Pmu_g[k * 64 + tid] = s;
  }
  __syncthreads();
  if (tid == 0) {
    float s = 0.f;
    for (int i = 0; i < 64; ++i) s += mu[k * 64 + i] * Pmu_s[i];
    e_g[k] = c[k] - 0.5f * s;
  }
  // A-frag swizzle for main GEMM: frag f=(mt,s): val = P[dim_in][dim_out]
  // dim_in = s*32 + q*8 + j, dim_out = mt*16 + low4   (A[m][kk] = P[kk][m])
  for (int idx = tid; idx < 4096; ++idx) {
    // strided loop below (bugproof: use += 256)
    break;
  }
  for (int idx = tid; idx < 4096; idx += 256) {
    int f = idx >> 9, lane = (idx >> 3) & 63, j = idx & 7;
    int mt = f >> 1, s = f & 1, qq = lane >> 4, l4 = lane & 15;
    float v = Pk[(s * 32 + qq * 8 + j) * 64 + mt * 16 + l4];
    Psw[k * 4096 + idx] = __float2bfloat16(v);
  }
}

// ---------------- precompute 2: Pmu fragment swizzles -----------------------
__global__ void precompute2(const float* __restrict__ Pmu_g,
                            __hip_bfloat16* __restrict__ PmuA,
                            __hip_bfloat16* __restrict__ PmuB) {
  const int tid = threadIdx.x;
  // PmuA (pmx GEMM A-operand): A[m=cluster][kk=dim]; frag f=(mtc,s)
  for (int idx = tid; idx < 2048; idx += 256) {
    int f = idx >> 9, lane = (idx >> 3) & 63, j = idx & 7;
    int mtc = f >> 1, s = f & 1, qq = lane >> 4, l4 = lane & 15;
    PmuA[idx] = __float2bfloat16(Pmu_g[(mtc * 16 + l4) * 64 + s * 32 + qq * 8 + j]);
  }
  // PmuB (pmuacc GEMM A-operand): A[m=dim][kk=cluster]; frag f=mtd (K=32, 1 step)
  for (int idx = tid; idx < 2048; idx += 256) {
    int f = idx >> 9, lane = (idx >> 3) & 63, j = idx & 7;
    int qq = lane >> 4, l4 = lane & 15;
    PmuB[idx] = __float2bfloat16(Pmu_g[(qq * 8 + j) * 64 + f * 16 + l4]);
  }
}

// ---------------- main kernel ----------------------------------------------
// block = 256 thr (4 waves), 32 pts/wave, 128 pts/block, grid = 512
__launch_bounds__(256, 2)
__global__ void denoise_main(const float* __restrict__ x_in,
                             const float* __restrict__ e_g,
                             const float* __restrict__ alpha_g,
                             const __hip_bfloat16* __restrict__ Psw,
                             const __hip_bfloat16* __restrict__ PmuA,
                             const __hip_bfloat16* __restrict__ PmuB,
                             float* __restrict__ out) {
  __shared__ __attribute__((aligned(16))) __hip_bfloat16 pbuf[2 * 4096];      // P dbuf 16KB
  __shared__ __attribute__((aligned(16))) __hip_bfloat16 xs[4 * 32 * XS_PAD]; // 18KB
  __shared__ __attribute__((aligned(16))) float pmxs[4 * 32 * 32];            // 16KB
  __shared__ __attribute__((aligned(16))) __hip_bfloat16 wts[4 * 32 * 32];    // 8KB

  const int tid = threadIdx.x;
  const int wave = tid >> 6, lane = tid & 63;
  const int q = lane >> 4, l4 = lane & 15;
  const int base_pt = blockIdx.x * 128 + wave * 32;
  const float alpha = alpha_g[0];

  __hip_bfloat16* xsw = xs + wave * 32 * XS_PAD;
  float* pmxw = pmxs + wave * 1024;
  __hip_bfloat16* wtw = wts + wave * 1024;

  // x master, C-layout: xm[mt][nt][r] = x[dim = mt*16+q*4+r][pt = nt*16+l4]
  float xm[4][2][4];
#pragma unroll
  for (int mt = 0; mt < 4; ++mt)
#pragma unroll
    for (int nt = 0; nt < 2; ++nt)
#pragma unroll
      for (int r = 0; r < 4; ++r)
        xm[mt][nt][r] = x_in[(base_pt + nt * 16 + l4) * 64 + mt * 16 + q * 4 + r];

  const f32x4 Z4 = {0.f, 0.f, 0.f, 0.f};

#pragma unroll 1
  for (int it = 0; it < NITER; ++it) {
    // ---- stage x (bf16) into per-wave LDS rows [pt][dim] ----
#pragma unroll
    for (int mt = 0; mt < 4; ++mt)
#pragma unroll
      for (int nt = 0; nt < 2; ++nt)
#pragma unroll
        for (int r = 0; r < 4; ++r)
          xsw[(nt * 16 + l4) * XS_PAD + mt * 16 + q * 4 + r] =
              __float2bfloat16(xm[mt][nt][r]);

    // ---- B-frags of x: B[kk=dim=s*32+q*8+j][n=pt=l4] (constant over k) ----
    bf16x8 bx[2][2];
#pragma unroll
    for (int s = 0; s < 2; ++s)
#pragma unroll
      for (int nt = 0; nt < 2; ++nt)
        bx[s][nt] = *(const bf16x8*)&xsw[(nt * 16 + l4) * XS_PAD + s * 32 + q * 8];

    // ---- prefetch P(k=0) into buf0 (each wave stages frags wave, wave+4) ----
    {
      const char* g = (const char*)Psw + 0 * 8192 + wave * 1024 + lane * 16;
      char* l = (char*)&pbuf[0] + 0 * 8192 + wave * 1024;
      gl_lds16(g, l);
      gl_lds16(g + 4096, l + 4096);
    }

    // ---- pmx GEMM: pmx[cluster][pt] = sum_dim Pmu[cluster][dim]*x[dim][pt] ----
    f32x4 pmx[2][2];
#pragma unroll
    for (int mtc = 0; mtc < 2; ++mtc)
#pragma unroll
      for (int nt = 0; nt < 2; ++nt) {
        f32x4 acc = Z4;
#pragma unroll
        for (int s = 0; s < 2; ++s) {
          bf16x8 a = *(const bf16x8*)&PmuA[(mtc * 2 + s) * 512 + lane * 8];
          acc = __builtin_amdgcn_mfma_f32_16x16x32_bf16(a, bx[s][nt], acc, 0, 0, 0);
        }
        pmx[mtc][nt] = acc;
      }
    // spill pmx to per-wave LDS [cluster][pt] (k-loop reads it wave-uniformly)
#pragma unroll
    for (int mtc = 0; mtc < 2; ++mtc)
#pragma unroll
      for (int nt = 0; nt < 2; ++nt)
#pragma unroll
        for (int r = 0; r < 4; ++r)
          pmxw[(mtc * 16 + q * 4 + r) * 32 + nt * 16 + l4] = pmx[mtc][nt][r];

    float accY[4][2][4];
#pragma unroll
    for (int mt = 0; mt < 4; ++mt)
#pragma unroll
      for (int nt = 0; nt < 2; ++nt)
#pragma unroll
        for (int r = 0; r < 4; ++r) accY[mt][nt][r] = 0.f;
    float lsum0 = 0.f, lsum1 = 0.f;

    __syncthreads();  // P(k=0) staged (vmcnt drained at barrier)

    // ---- k-loop over clusters, double-buffered P ----
#pragma unroll 2
    for (int k = 0; k < KC; ++k) {
      const int buf = k & 1;
      if (k < KC - 1) {
        const char* g = (const char*)Psw + (k + 1) * 8192 + wave * 1024 + lane * 16;
        char* l = (char*)&pbuf[0] + (buf ^ 1) * 8192 + wave * 1024;
        gl_lds16(g, l);
        gl_lds16(g + 4096, l + 4096);
      }
      // A-frags of P: A[m=dim_out=mt*16+l4][kk=dim_in=s*32+q*8+j]
      const __hip_bfloat16* pb = &pbuf[buf * 4096];
      bf16x8 ap[4][2];
#pragma unroll
      for (int mt = 0; mt < 4; ++mt)
#pragma unroll
        for (int s = 0; s < 2; ++s)
          ap[mt][s] = *(const bf16x8*)&pb[(mt * 2 + s) * 512 + lane * 8];

      // y' = P x : C[row=dim=mt*16+q*4+r][col=pt=nt*16+l4]
      f32x4 y[4][2];
#pragma unroll
      for (int mt = 0; mt < 4; ++mt)
#pragma unroll
        for (int nt = 0; nt < 2; ++nt) {
          f32x4 acc = Z4;
          acc = __builtin_amdgcn_mfma_f32_16x16x32_bf16(ap[mt][0], bx[0][nt], acc, 0, 0, 0);
          acc = __builtin_amdgcn_mfma_f32_16x16x32_bf16(ap[mt][1], bx[1][nt], acc, 0, 0, 0);
          y[mt][nt] = acc;
        }

      // xy[pt] = x . y  (partials over this lane's 16 rows, then reduce over q)
      float xy0 = 0.f, xy1 = 0.f;
#pragma unroll
      for (int mt = 0; mt < 4; ++mt)
#pragma unroll
        for (int r = 0; r < 4; ++r) {
          xy0 += xm[mt][0][r] * y[mt][0][r];
          xy1 += xm[mt][1][r] * y[mt][1][r];
        }
      xy0 += __shfl_xor(xy0, 16, 64);
      xy0 += __shfl_xor(xy0, 32, 64);
      xy1 += __shfl_xor(xy1, 16, 64);
      xy1 += __shfl_xor(xy1, 32, 64);

      const float pk0 = pmxw[k * 32 + l4];
      const float pk1 = pmxw[k * 32 + 16 + l4];
      const float ek = e_g[k];
      const float s0 = ek + pk0 - 0.5f * xy0;
      const float s1 = ek + pk1 - 0.5f * xy1;
      const float w0 = __expf(s0);
      const float w1 = __expf(s1);
      lsum0 += w0;
      lsum1 += w1;
      // collect weights (bf16) for the end-of-iteration Pmu GEMM
      if (q == 0) {
        wtw[l4 * 32 + k] = __float2bfloat16(w0);
        wtw[(16 + l4) * 32 + k] = __float2bfloat16(w1);
      }
      // accY += w * y
#pragma unroll
      for (int mt = 0; mt < 4; ++mt)
#pragma unroll
        for (int r = 0; r < 4; ++r) {
          accY[mt][0][r] += w0 * y[mt][0][r];
          accY[mt][1][r] += w1 * y[mt][1][r];
        }
      __syncthreads();  // all waves done with pbuf[buf]; prefetch landed
    }

    // ---- pacc[dim][pt] = sum_k Pmu[k][dim] * wt[k][pt]  (one K=32 GEMM) ----
    bf16x8 wtf[2];
#pragma unroll
    for (int nt = 0; nt < 2; ++nt)
      wtf[nt] = *(const bf16x8*)&wtw[(nt * 16 + l4) * 32 + q * 8];
    f32x4 pacc[4][2];
#pragma unroll
    for (int mt = 0; mt < 4; ++mt) {
      bf16x8 a = *(const bf16x8*)&PmuB[mt * 512 + lane * 8];
#pragma unroll
      for (int nt = 0; nt < 2; ++nt)
        pacc[mt][nt] = __builtin_amdgcn_mfma_f32_16x16x32_bf16(a, wtf[nt], Z4, 0, 0, 0);
    }

    // ---- x += (alpha/l) * (pacc - accY) ----
    const float c0 = alpha / lsum0;
    const float c1 = alpha / lsum1;
#pragma unroll
    for (int mt = 0; mt < 4; ++mt)
#pragma unroll
      for (int r = 0; r < 4; ++r) {
        xm[mt][0][r] += c0 * (pacc[mt][0][r] - accY[mt][0][r]);
        xm[mt][1][r] += c1 * (pacc[mt][1][r] - accY[mt][1][r]);
      }
  }  // iterations

  // ---- coalesced output via per-wave LDS scratch (2 passes of 32 dims) ----
#pragma unroll
  for (int p = 0; p < 2; ++p) {
#pragma unroll
    for (int mt2 = 0; mt2 < 2; ++mt2)
#pragma unroll
      for (int nt = 0; nt < 2; ++nt)
#pragma unroll
        for (int r = 0; r < 4; ++r)
          pmxw[(nt * 16 + l4) * 32 + mt2 * 16 + q * 4 + r] = xm[p * 2 + mt2][nt][r];
#pragma unroll
    for (int rep = 0; rep < 16; ++rep) {
      int flat = rep * 64 + lane;
      int pt = flat >> 5, dp = flat & 31;
      out[(base_pt + pt) * 64 + p * 32 + dp] = pmxw[pt * 32 + dp];
    }
  }
}

extern "C" void kernel_launch(void* const* d_in, const int* in_sizes, int n_in,
                              void* d_out, int out_size, void* d_ws, size_t ws_size,
                              hipStream_t stream) {
  (void)in_sizes; (void)n_in; (void)out_size; (void)ws_size;
  const float* x = (const float*)d_in[0];
  const float* c = (const float*)d_in[1];
  const float* mu = (const float*)d_in[2];
  const float* A = (const float*)d_in[3];
  const float* alpha = (const float*)d_in[4];
  float* out = (float*)d_out;

  char* ws = (char*)d_ws;
  float* Pmu_g = (float*)(ws);                           // 8192 B
  float* e_g = (float*)(ws + 8192);                      // 128 B (pad to 256)
  __hip_bfloat16* PmuA = (__hip_bfloat16*)(ws + 8448);   // 4096 B
  __hip_bfloat16* PmuB = (__hip_bfloat16*)(ws + 12544);  // 4096 B
  __hip_bfloat16* Psw = (__hip_bfloat16*)(ws + 16640);   // 262144 B

  precompute1<<<32, 256, 0, stream>>>(A, mu, c, Pmu_g, e_g, Psw);
  precompute2<<<1, 256, 0, stream>>>(Pmu_g, PmuA, PmuB);
  denoise_main<<<512, 256, 0, stream>>>(x, e_g, alpha, Psw, PmuA, PmuB, out);
}

// Round 3
// 310.643 us; speedup vs baseline: 1.0292x; 1.0292x over previous
//
#include <hip/hip_runtime.h>
#include <hip/hip_bf16.h>

// DenoisingPotential: x_{t+1} = x_t + alpha * grad_phi(x_t), 10 iters.
// grad = -(sum_k w_k * (P_k x - P_k mu_k)),  w = softmax(c - 0.5*quad)
// Restructured: s_k = e_k + (Pmu_k . x) - 0.5*(x . y_k), y_k = P_k x
// x += (alpha/l) * (sum_k wt_k Pmu_k - sum_k wt_k y_k),  wt = exp(s), l = sum wt
// (c=0 and quad>=0 => s<=0: no softmax max-shift needed)
//
// R3: R2's barrier-free LDS scheme raced (global_load_lds completion is only
// visible via vmcnt; ds_read had no dependency -> stale LDS -> NaN). Fix:
// P fragments are stored in exact per-lane order, so load them straight into
// VGPRs (register double-buffer ap[2][4][2]) -- dependencies fully
// compiler-tracked, zero barriers, zero LDS traffic for P.

typedef __attribute__((ext_vector_type(4))) float f32x4;
typedef __attribute__((ext_vector_type(8))) short bf16x8;  // 8 bf16 = 4 VGPRs

#define KC 32
#define NITER 10
#define XROW 72        // bf16 elems per point-row in xs staging (pad vs 64)
#define WAVE_SCR 6656  // per-wave scratch bytes: xs/pmx 4608 + wt 2048

static __device__ __forceinline__ unsigned pk_bf16(float a, float b) {
  __hip_bfloat16 ha = __float2bfloat16(a), hb = __float2bfloat16(b);
  unsigned short ua = *(unsigned short*)&ha, ub = *(unsigned short*)&hb;
  return (unsigned)ua | ((unsigned)ub << 16);
}

// ---------------- precompute 1: per-k P = A^T A, Pmu, e, swizzled P ----------
__global__ void precompute1(const float* __restrict__ A, const float* __restrict__ mu,
                            const float* __restrict__ c,
                            float* __restrict__ Pmu_g, float* __restrict__ e_g,
                            __hip_bfloat16* __restrict__ Psw) {
  __shared__ float Pk[64 * 64];
  __shared__ float Pmu_s[64];
  const int k = blockIdx.x, tid = threadIdx.x;
  const float* Ak = A + k * 4096;
  for (int idx = tid; idx < 4096; idx += 256) {
    int i = idx >> 6, l = idx & 63;
    float s = 0.f;
    for (int j = 0; j < 64; ++j) s += Ak[j * 64 + i] * Ak[j * 64 + l];
    Pk[idx] = s;  // P[i][l], exactly symmetric
  }
  __syncthreads();
  if (tid < 64) {
    float s = 0.f;
    for (int l = 0; l < 64; ++l) s += Pk[tid * 64 + l] * mu[k * 64 + l];
    Pmu_s[tid] = s;
    Pmu_g[k * 64 + tid] = s;
  }
  __syncthreads();
  if (tid == 0) {
    float s = 0.f;
    for (int i = 0; i < 64; ++i) s += mu[k * 64 + i] * Pmu_s[i];
    e_g[k] = c[k] - 0.5f * s;
  }
  // A-frag order for the main GEMM: flat idx = f*512 + lane*8 + j,
  // f=(mt,s): val = P[dim_in = s*32 + q*8 + j][dim_out = mt*16 + l4]
  for (int idx = tid; idx < 4096; idx += 256) {
    int f = idx >> 9, lane = (idx >> 3) & 63, j = idx & 7;
    int mt = f >> 1, s = f & 1, qq = lane >> 4, l4 = lane & 15;
    float v = Pk[(s * 32 + qq * 8 + j) * 64 + mt * 16 + l4];
    Psw[k * 4096 + idx] = __float2bfloat16(v);
  }
}

// ---------------- precompute 2: Pmu fragment swizzles -----------------------
__global__ void precompute2(const float* __restrict__ Pmu_g,
                            __hip_bfloat16* __restrict__ PmuA,
                            __hip_bfloat16* __restrict__ PmuB) {
  const int tid = threadIdx.x;
  // PmuA (pmx GEMM A-operand): A[m=cluster][kk=dim]; frag f=(mtc,s)
  for (int idx = tid; idx < 2048; idx += 256) {
    int f = idx >> 9, lane = (idx >> 3) & 63, j = idx & 7;
    int mtc = f >> 1, s = f & 1, qq = lane >> 4, l4 = lane & 15;
    PmuA[idx] = __float2bfloat16(Pmu_g[(mtc * 16 + l4) * 64 + s * 32 + qq * 8 + j]);
  }
  // PmuB (pacc GEMM A-operand): A[m=dim][kk=cluster]; frag f=mtd (K=32, 1 step)
  for (int idx = tid; idx < 2048; idx += 256) {
    int f = idx >> 9, lane = (idx >> 3) & 63, j = idx & 7;
    int qq = lane >> 4, l4 = lane & 15;
    PmuB[idx] = __float2bfloat16(Pmu_g[(qq * 8 + j) * 64 + f * 16 + l4]);
  }
}

// ---------------- main kernel ----------------------------------------------
// 256 thr (4 waves), 32 pts/wave, grid 512. NO __syncthreads anywhere; all
// LDS use is wave-private scratch. P comes via register double-buffer.
__launch_bounds__(256, 2)
__global__ void denoise_main(const float* __restrict__ x_in,
                             const float* __restrict__ e_g,
                             const float* __restrict__ alpha_g,
                             const __hip_bfloat16* __restrict__ Psw,
                             const __hip_bfloat16* __restrict__ PmuA,
                             const __hip_bfloat16* __restrict__ PmuB,
                             float* __restrict__ out) {
  __shared__ __attribute__((aligned(16))) char scratch[4 * WAVE_SCR];  // 26 KB

  const int tid = threadIdx.x;
  const int wave = tid >> 6, lane = tid & 63;
  const int q = lane >> 4, l4 = lane & 15;
  const int base_pt = blockIdx.x * 128 + wave * 32;
  const float alpha = alpha_g[0];

  char* sw = scratch + wave * WAVE_SCR;
  __hip_bfloat16* xsw = (__hip_bfloat16*)sw;           // 32*XROW*2 = 4608 B
  float* pmxw = (float*)sw;                            // 4096 B (xs dead by then)
  __hip_bfloat16* wtw = (__hip_bfloat16*)(sw + 4608);  // 2048 B

  const bf16x8* PswF = (const bf16x8*)Psw;    // frag idx = k*512 + f*64 + lane
  const bf16x8* PmuAF = (const bf16x8*)PmuA;  // frag idx = f*64 + lane
  const bf16x8* PmuBF = (const bf16x8*)PmuB;

  // x master, C-layout: xm[mt][nt][r] = x[dim = mt*16+q*4+r][pt = nt*16+l4]
  float xm[4][2][4];
#pragma unroll
  for (int mt = 0; mt < 4; ++mt)
#pragma unroll
    for (int nt = 0; nt < 2; ++nt)
#pragma unroll
      for (int r = 0; r < 4; ++r)
        xm[mt][nt][r] = x_in[(base_pt + nt * 16 + l4) * 64 + mt * 16 + q * 4 + r];

  const f32x4 Z4 = {0.f, 0.f, 0.f, 0.f};

#pragma unroll 1
  for (int it = 0; it < NITER; ++it) {
    // ---- stage x (bf16) into wave-private rows [pt][dim], XROW-padded ----
#pragma unroll
    for (int mt = 0; mt < 4; ++mt)
#pragma unroll
      for (int nt = 0; nt < 2; ++nt) {
        unsigned u0 = pk_bf16(xm[mt][nt][0], xm[mt][nt][1]);
        unsigned u1 = pk_bf16(xm[mt][nt][2], xm[mt][nt][3]);
        uint2 v; v.x = u0; v.y = u1;
        *(uint2*)&xsw[(nt * 16 + l4) * XROW + mt * 16 + q * 4] = v;
      }

    // ---- B-frags of x: B[kk=dim=s*32+q*8+j][n=pt=l4] (constant over k) ----
    bf16x8 bx[2][2];
#pragma unroll
    for (int s = 0; s < 2; ++s)
#pragma unroll
      for (int nt = 0; nt < 2; ++nt)
        bx[s][nt] = *(const bf16x8*)&xsw[(nt * 16 + l4) * XROW + s * 32 + q * 8];

    // ---- preload P(k=0) fragments into register buffer 0 ----
    bf16x8 ap[2][4][2];
#pragma unroll
    for (int mt = 0; mt < 4; ++mt)
#pragma unroll
      for (int s = 0; s < 2; ++s)
        ap[0][mt][s] = PswF[(mt * 2 + s) * 64 + lane];

    // ---- pmx GEMM: pmx[cluster][pt] = sum_dim Pmu[cluster][dim]*x[dim][pt] ----
    f32x4 pmx[2][2];
#pragma unroll
    for (int mtc = 0; mtc < 2; ++mtc)
#pragma unroll
      for (int nt = 0; nt < 2; ++nt) {
        f32x4 acc = Z4;
#pragma unroll
        for (int s = 0; s < 2; ++s) {
          bf16x8 a = PmuAF[(mtc * 2 + s) * 64 + lane];
          acc = __builtin_amdgcn_mfma_f32_16x16x32_bf16(a, bx[s][nt], acc, 0, 0, 0);
        }
        pmx[mtc][nt] = acc;
      }
    // spill pmx to wave-private LDS [cluster][pt] f32 (xs region is dead now)
#pragma unroll
    for (int mtc = 0; mtc < 2; ++mtc)
#pragma unroll
      for (int nt = 0; nt < 2; ++nt)
#pragma unroll
        for (int r = 0; r < 4; ++r)
          pmxw[(mtc * 16 + q * 4 + r) * 32 + nt * 16 + l4] = pmx[mtc][nt][r];

    float accY[4][2][4];
#pragma unroll
    for (int mt = 0; mt < 4; ++mt)
#pragma unroll
      for (int nt = 0; nt < 2; ++nt)
#pragma unroll
        for (int r = 0; r < 4; ++r) accY[mt][nt][r] = 0.f;
    float lsum0 = 0.f, lsum1 = 0.f;

    // ---- k-loop: register-double-buffered P, no barriers ----
#pragma unroll 2
    for (int k = 0; k < KC; ++k) {
      const int cur = k & 1, nxt = cur ^ 1;
      const int kn = (k + 1) & (KC - 1);  // wraps to 0 on last step (harmless)
      // issue next-k fragment loads first (they overlap this step's compute)
#pragma unroll
      for (int mt = 0; mt < 4; ++mt)
#pragma unroll
        for (int s = 0; s < 2; ++s)
          ap[nxt][mt][s] = PswF[kn * 512 + (mt * 2 + s) * 64 + lane];

      // y' = P x : C[row=dim=mt*16+q*4+r][col=pt=nt*16+l4]
      f32x4 y[4][2];
#pragma unroll
      for (int mt = 0; mt < 4; ++mt)
#pragma unroll
        for (int nt = 0; nt < 2; ++nt) {
          f32x4 acc = Z4;
          acc = __builtin_amdgcn_mfma_f32_16x16x32_bf16(ap[cur][mt][0], bx[0][nt], acc, 0, 0, 0);
          acc = __builtin_amdgcn_mfma_f32_16x16x32_bf16(ap[cur][mt][1], bx[1][nt], acc, 0, 0, 0);
          y[mt][nt] = acc;
        }

      // xy[pt] = x . y (partials over this lane's 16 rows, reduce over quads)
      float xy0 = 0.f, xy1 = 0.f;
#pragma unroll
      for (int mt = 0; mt < 4; ++mt)
#pragma unroll
        for (int r = 0; r < 4; ++r) {
          xy0 += xm[mt][0][r] * y[mt][0][r];
          xy1 += xm[mt][1][r] * y[mt][1][r];
        }
      xy0 += __shfl_xor(xy0, 16, 64);
      xy0 += __shfl_xor(xy0, 32, 64);
      xy1 += __shfl_xor(xy1, 16, 64);
      xy1 += __shfl_xor(xy1, 32, 64);

      const float pk0 = pmxw[k * 32 + l4];
      const float pk1 = pmxw[k * 32 + 16 + l4];
      const float ek = e_g[k];
      const float w0 = __expf(ek + pk0 - 0.5f * xy0);
      const float w1 = __expf(ek + pk1 - 0.5f * xy1);
      lsum0 += w0;
      lsum1 += w1;
      // stash weights (bf16) for the end-of-iteration Pmu GEMM (wave-private)
      if (q == 0) {
        wtw[l4 * 32 + k] = __float2bfloat16(w0);
        wtw[(16 + l4) * 32 + k] = __float2bfloat16(w1);
      }
      // accY += w * y
#pragma unroll
      for (int mt = 0; mt < 4; ++mt)
#pragma unroll
        for (int r = 0; r < 4; ++r) {
          accY[mt][0][r] += w0 * y[mt][0][r];
          accY[mt][1][r] += w1 * y[mt][1][r];
        }
    }

    // ---- pacc[dim][pt] = sum_k Pmu[k][dim] * wt[k][pt]  (one K=32 GEMM) ----
    bf16x8 wtf[2];
#pragma unroll
    for (int nt = 0; nt < 2; ++nt)
      wtf[nt] = *(const bf16x8*)&wtw[(nt * 16 + l4) * 32 + q * 8];
    f32x4 pacc[4][2];
#pragma unroll
    for (int mt = 0; mt < 4; ++mt) {
      bf16x8 a = PmuBF[mt * 64 + lane];
      pacc[mt][0] = __builtin_amdgcn_mfma_f32_16x16x32_bf16(a, wtf[0], Z4, 0, 0, 0);
      pacc[mt][1] = __builtin_amdgcn_mfma_f32_16x16x32_bf16(a, wtf[1], Z4, 0, 0, 0);
    }

    // ---- x += (alpha/l) * (pacc - accY) ----
    const float c0 = alpha / lsum0;
    const float c1 = alpha / lsum1;
#pragma unroll
    for (int mt = 0; mt < 4; ++mt)
#pragma unroll
      for (int r = 0; r < 4; ++r) {
        xm[mt][0][r] += c0 * (pacc[mt][0][r] - accY[mt][0][r]);
        xm[mt][1][r] += c1 * (pacc[mt][1][r] - accY[mt][1][r]);
      }
  }  // iterations

  // ---- coalesced output via wave-private scratch (2 passes of 32 dims) ----
  float* outs = (float*)sw;
#pragma unroll
  for (int p = 0; p < 2; ++p) {
#pragma unroll
    for (int mt2 = 0; mt2 < 2; ++mt2)
#pragma unroll
      for (int nt = 0; nt < 2; ++nt)
#pragma unroll
        for (int r = 0; r < 4; ++r)
          outs[(nt * 16 + l4) * 32 + mt2 * 16 + q * 4 + r] = xm[p * 2 + mt2][nt][r];
#pragma unroll
    for (int rep = 0; rep < 16; ++rep) {
      int flat = rep * 64 + lane;
      int pt = flat >> 5, dp = flat & 31;
      out[(base_pt + pt) * 64 + p * 32 + dp] = outs[pt * 32 + dp];
    }
  }
}

extern "C" void kernel_launch(void* const* d_in, const int* in_sizes, int n_in,
                              void* d_out, int out_size, void* d_ws, size_t ws_size,
                              hipStream_t stream) {
  (void)in_sizes; (void)n_in; (void)out_size; (void)ws_size;
  const float* x = (const float*)d_in[0];
  const float* c = (const float*)d_in[1];
  const float* mu = (const float*)d_in[2];
  const float* A = (const float*)d_in[3];
  const float* alpha = (const float*)d_in[4];
  float* out = (float*)d_out;

  char* ws = (char*)d_ws;
  float* Pmu_g = (float*)(ws);                           // 8192 B
  float* e_g = (float*)(ws + 8192);                      // 128 B (pad to 256)
  __hip_bfloat16* PmuA = (__hip_bfloat16*)(ws + 8448);   // 4096 B
  __hip_bfloat16* PmuB = (__hip_bfloat16*)(ws + 12544);  // 4096 B
  __hip_bfloat16* Psw = (__hip_bfloat16*)(ws + 16640);   // 262144 B

  precompute1<<<32, 256, 0, stream>>>(A, mu, c, Pmu_g, e_g, Psw);
  precompute2<<<1, 256, 0, stream>>>(Pmu_g, PmuA, PmuB);
  denoise_main<<<512, 256, 0, stream>>>(x, e_g, alpha, Psw, PmuA, PmuB, out);
}